// Round 13
// baseline (510.031 us; speedup 1.0000x reference)
//
#include <hip/hip_runtime.h>

typedef __bf16 bf16;
typedef __bf16 bf16x4 __attribute__((ext_vector_type(4)));
typedef __bf16 bf16x8 __attribute__((ext_vector_type(8)));
typedef float f32x4 __attribute__((ext_vector_type(4)));

#define B_ 2
#define S_ 2048
#define D_ 2048
#define H_ 16
#define DH_ 128
#define QKVN 6144

__device__ __forceinline__ void async_load16(const bf16* g, bf16* l) {
    __builtin_amdgcn_global_load_lds((const __attribute__((address_space(1))) void*)g,
                                     (__attribute__((address_space(3))) void*)l, 16, 0, 0);
}

__device__ __forceinline__ unsigned int bf16_bits(float x) {
    bf16 h = (bf16)x;
    return (unsigned int)__builtin_bit_cast(unsigned short, h);
}

// ======== merged prep: x cast (blocks 0..4095) + 4x weight transpose (4096..8191) =
__global__ __launch_bounds__(256) void prep_kernel(const float* __restrict__ x,
                                                   const float* __restrict__ Wq,
                                                   const float* __restrict__ Wk,
                                                   const float* __restrict__ Wv,
                                                   const float* __restrict__ Wo,
                                                   bf16* __restrict__ xb,
                                                   bf16* __restrict__ WqkvT,
                                                   bf16* __restrict__ WoT) {
    __shared__ unsigned int tile[64][65];  // used by wtrans half only
    int bid = blockIdx.x;
    int t = threadIdx.x;
    if (bid < 4096) {
        // ---- cvt: f32 -> bf16, 8 elems/thread ----
        size_t i = (size_t)bid * 256 + t;
        const float4* s = (const float4*)x;
        float4 a = s[2 * i], b = s[2 * i + 1];
        bf16x8 o;
        o[0] = (bf16)a.x; o[1] = (bf16)a.y; o[2] = (bf16)a.z; o[3] = (bf16)a.w;
        o[4] = (bf16)b.x; o[5] = (bf16)b.y; o[6] = (bf16)b.z; o[7] = (bf16)b.w;
        *(bf16x8*)(xb + 8 * i) = o;
        return;
    }
    // ---- wtrans: W[K][N] f32 -> Wt[N][K] bf16, 4 matrices ----
    int rbid = bid - 4096;             // 0..4095
    int z = rbid >> 10;                // matrix id
    int by = (rbid >> 5) & 31, bx = rbid & 31;
    const float* src = (z == 0) ? Wq : (z == 1) ? Wk : (z == 2) ? Wv : Wo;
    bf16* dst = (z < 3) ? (WqkvT + (size_t)z * D_ * D_) : WoT;
    int r0 = by * 64, c0 = bx * 64;
    int tr = t >> 4, tc4 = (t & 15) * 4;
#pragma unroll
    for (int it = 0; it < 4; ++it) {
        int r = it * 16 + tr;
        float4 v = *(const float4*)(src + (size_t)(r0 + r) * D_ + c0 + tc4);
        tile[r][tc4 + 0] = bf16_bits(v.x);
        tile[r][tc4 + 1] = bf16_bits(v.y);
        tile[r][tc4 + 2] = bf16_bits(v.z);
        tile[r][tc4 + 3] = bf16_bits(v.w);
    }
    __syncthreads();
#pragma unroll
    for (int it = 0; it < 4; ++it) {
        int a = it * 16 + tr;
        unsigned u0 = tile[tc4 + 0][a], u1 = tile[tc4 + 1][a];
        unsigned u2 = tile[tc4 + 2][a], u3 = tile[tc4 + 3][a];
        uint2 v;
        v.x = (u0 & 0xffffu) | (u1 << 16);
        v.y = (u2 & 0xffffu) | (u3 << 16);
        *(uint2*)(dst + (size_t)(c0 + a) * D_ + r0 + tc4) = v;
    }
}

// ========== shared pieces for 256x128-tile GEMMs ==================================
#define QK_K 2048
#define QK_N 6144

__device__ __forceinline__ bf16x8 lds_frag(const bf16* tile, int row, int colByte) {
    int off = row * 128 + (colByte ^ ((row & 7) << 4));
    return *(const bf16x8*)((const char*)tile + off);
}

template <int MH>
__device__ __forceinline__ void mmaq16(f32x4 (&acc)[8][2], const bf16x8 (&afr)[4][2],
                                       const bf16x8 (&bf)[2][2]) {
    __builtin_amdgcn_s_setprio(1);
#pragma unroll
    for (int i = 0; i < 4; ++i)
#pragma unroll
        for (int j = 0; j < 2; ++j)
#pragma unroll
            for (int kk = 0; kk < 2; ++kk)
                acc[MH * 4 + i][j] = __builtin_amdgcn_mfma_f32_16x16x32_bf16(
                    afr[i][kk], bf[j][kk], acc[MH * 4 + i][j], 0, 0, 0);
    __builtin_amdgcn_s_setprio(0);
}

// ========== 256x128-tile GEMM (r7 schedule, FROZEN), templated on N/out-type ======
// V panels (NPAN=48, n0>=4096) write transposed vt[bh][dh][s] via LDS bounce
// (r12: coalesced 512B rows; qkv cost recovered vs r11's scattered stores).
template <int NPAN, typename CT>
__global__ __launch_bounds__(512, 2) void gemm_256x128(const bf16* __restrict__ A,
                                                       const bf16* __restrict__ Bt,
                                                       CT* __restrict__ C,
                                                       bf16* __restrict__ VT) {
    __shared__ __align__(16) bf16 As[3][256 * 64];  // 96 KB
    __shared__ __align__(16) bf16 Bs[3][128 * 64];  // 48 KB

    const int NN = NPAN * 128;
    int t = threadIdx.x;
    int wid = t >> 6, lane = t & 63;
    int quad = lane >> 4, lr = lane & 15;
    int wr = wid >> 2, wn = wid & 3;  // 2 (M) x 4 (N) wave grid

    int bid = blockIdx.x;
    int swz = (bid & 7) * (2 * NPAN) + (bid >> 3);  // 16*NPAN/8 per XCD
    int tn = swz >> 4, tm = swz & 15;
    size_t m0 = (size_t)tm * 256, n0 = (size_t)tn * 128;

    int row_r[2], c8s_r[2];
#pragma unroll
    for (int r = 0; r < 2; ++r) {
        int idx = r * 512 + t;
        row_r[r] = idx >> 3;
        c8s_r[r] = (idx & 7) ^ (row_r[r] & 7);
    }

    auto stA = [&](int kt, int bufi, int h) {
#pragma unroll
        for (int r = 0; r < 2; ++r)
            async_load16(A + (m0 + h * 128 + row_r[r]) * (size_t)QK_K + kt * 64 + c8s_r[r] * 8,
                         &As[bufi][(h * 1024 + r * 512 + wid * 64) * 8]);
    };
    auto stB = [&](int kt, int bufi) {
#pragma unroll
        for (int r = 0; r < 2; ++r)
            async_load16(Bt + (n0 + row_r[r]) * (size_t)QK_K + kt * 64 + c8s_r[r] * 8,
                         &Bs[bufi][(r * 512 + wid * 64) * 8]);
    };

    f32x4 acc[8][2];
#pragma unroll
    for (int i = 0; i < 8; ++i)
#pragma unroll
        for (int j = 0; j < 2; ++j) acc[i][j] = (f32x4){0.f, 0.f, 0.f, 0.f};

    bf16x8 afr[4][2], bf[2][2];

    auto readA = [&](int bufi, int mh) {
#pragma unroll
        for (int i = 0; i < 4; ++i)
#pragma unroll
            for (int kk = 0; kk < 2; ++kk)
                afr[i][kk] = lds_frag(As[bufi], mh * 128 + wr * 64 + i * 16 + lr, kk * 64 + quad * 16);
    };
    auto readB = [&](int bufi) {
#pragma unroll
        for (int j = 0; j < 2; ++j)
#pragma unroll
            for (int kk = 0; kk < 2; ++kk)
                bf[j][kk] = lds_frag(Bs[bufi], wn * 32 + j * 16 + lr, kk * 64 + quad * 16);
    };

    stB(0, 0); stA(0, 0, 0); stA(0, 0, 1);
    stB(1, 1); stA(1, 1, 0); stA(1, 1, 1);
    asm volatile("s_waitcnt vmcnt(8)" ::: "memory");
    __builtin_amdgcn_s_barrier();

    auto tile2ph = [&](int kt, int cb, int nb2) {
        readA(cb, 0);
        readB(cb);
        stB(kt + 2, nb2);
        stA(kt + 2, nb2, 0);
        __builtin_amdgcn_s_barrier();
        asm volatile("s_waitcnt lgkmcnt(0)" ::: "memory");
        __builtin_amdgcn_sched_barrier(0);
        mmaq16<0>(acc, afr, bf);
        asm volatile("s_waitcnt vmcnt(10)" ::: "memory");
        __builtin_amdgcn_s_barrier();
        readA(cb, 1);
        stA(kt + 2, nb2, 1);
        __builtin_amdgcn_s_barrier();
        asm volatile("s_waitcnt lgkmcnt(0)" ::: "memory");
        __builtin_amdgcn_sched_barrier(0);
        mmaq16<1>(acc, afr, bf);
        asm volatile("s_waitcnt vmcnt(8)" ::: "memory");
        __builtin_amdgcn_s_barrier();
    };

    for (int kt3 = 0; kt3 < 30; kt3 += 3) {
        tile2ph(kt3 + 0, 0, 2);
        tile2ph(kt3 + 1, 1, 0);
        tile2ph(kt3 + 2, 2, 1);
    }

    {  // tail: tiles 30 (buf0) and 31 (buf1)
        readA(0, 0);
        readB(0);
        __builtin_amdgcn_s_barrier();
        asm volatile("s_waitcnt lgkmcnt(0)" ::: "memory");
        __builtin_amdgcn_sched_barrier(0);
        mmaq16<0>(acc, afr, bf);
        asm volatile("s_waitcnt vmcnt(6)" ::: "memory");
        __builtin_amdgcn_s_barrier();
        readA(0, 1);
        __builtin_amdgcn_s_barrier();
        asm volatile("s_waitcnt lgkmcnt(0)" ::: "memory");
        __builtin_amdgcn_sched_barrier(0);
        mmaq16<1>(acc, afr, bf);
        asm volatile("s_waitcnt vmcnt(2)" ::: "memory");
        __builtin_amdgcn_s_barrier();
        readA(1, 0);
        readB(1);
        __builtin_amdgcn_s_barrier();
        asm volatile("s_waitcnt lgkmcnt(0)" ::: "memory");
        __builtin_amdgcn_sched_barrier(0);
        mmaq16<0>(acc, afr, bf);
        asm volatile("s_waitcnt vmcnt(0)" ::: "memory");
        __builtin_amdgcn_s_barrier();
        readA(1, 1);
        asm volatile("s_waitcnt lgkmcnt(0)" ::: "memory");
        __builtin_amdgcn_sched_barrier(0);
        mmaq16<1>(acc, afr, bf);
    }

    if constexpr (NPAN == 48) {
        if (n0 >= 4096) {
            // V panel: transpose via LDS bounce (As is dead), then coalesced store.
            int h = (int)((n0 - 4096) >> 7);
            size_t b = m0 >> 11;        // 2048-row batches; 256-row tiles never straddle
            size_t s0 = m0 & 2047;
            bf16* vtb = VT + (b * 16 + h) * (size_t)(DH_ * S_);
            bf16* vl = &As[0][0];       // [128][264] padded: 67584 B <= 98304 B
            const int SP = 264;
            __builtin_amdgcn_s_barrier();
#pragma unroll
            for (int mh = 0; mh < 2; ++mh)
#pragma unroll
                for (int i = 0; i < 4; ++i)
#pragma unroll
                    for (int j = 0; j < 2; ++j) {
                        int dh = wn * 32 + j * 16 + lr;
                        int sl = mh * 128 + wr * 64 + i * 16 + quad * 4;
                        bf16x4 pk;
#pragma unroll
                        for (int r = 0; r < 4; ++r) pk[r] = (bf16)acc[mh * 4 + i][j][r];
                        *(bf16x4*)(vl + dh * SP + sl) = pk;
                    }
            __builtin_amdgcn_s_barrier();
#pragma unroll
            for (int pass = 0; pass < 8; ++pass) {
                int dh = pass * 16 + (t >> 5);
                int si = (t & 31) * 8;
                bf16x8 v = *(const bf16x8*)(vl + dh * SP + si);
                *(bf16x8*)(vtb + (size_t)dh * S_ + s0 + si) = v;
            }
            return;
        }
    }

#pragma unroll
    for (int mh = 0; mh < 2; ++mh)
#pragma unroll
        for (int i = 0; i < 4; ++i)
#pragma unroll
            for (int j = 0; j < 2; ++j)
#pragma unroll
                for (int r = 0; r < 4; ++r) {
                    size_t row = m0 + mh * 128 + wr * 64 + i * 16 + quad * 4 + r;
                    size_t col = n0 + wn * 32 + j * 16 + lr;
                    C[row * (size_t)NN + col] = (CT)acc[mh * 4 + i][j][r];
                }
}

// ---------------- flash attention, causal (r13: key-split waves) ------------------
// r13 change: waves split (q-rows x keys) as (wr,wc): rows [32wr,+32) x keys
// [32wc,+32). Each kf/vf ds_read_b128 now feeds 2 MFMAs (was 1) -> per-iter
// LDS b128 reads halved 32->16 (attn was LDS-pipe-bound). Ps stays wave-private
// (no per-iter barriers added). Key-split partials (O in f32, L) are combined
// once per q-tile via the then-dead Ks/Vts[buf] slabs (16 KB each, exact fit)
// + tiny Lx; 2 syncthreads per epilogue. Occupancy unchanged (2 blocks/CU).
__global__ __launch_bounds__(256, 2) void attn_kernel(const bf16* __restrict__ qkv,
                                                      const bf16* __restrict__ vt,
                                                      bf16* __restrict__ ctx) {
    __shared__ __align__(16) bf16 Ks[2][64 * 128];    // [key][16B-chunk c ^ (key&7)]
    __shared__ __align__(16) bf16 Vts[2][128 * 64];   // [dh][16B-chunk c ^ (dh&7)]
    __shared__ __align__(16) bf16 Ps[4][32 * 36];     // per-wave P [32q][32k], pad 4
    __shared__ float Lx[2][2][16];

    int flat = blockIdx.y * 16 + blockIdx.x;
    int sid = (flat & 7) * 64 + (flat >> 3);
    int y = sid >> 4;
    int p = sid & 15;
    int b = y >> 4, h = y & 15;
    int t = threadIdx.x, w = t >> 6, l = t & 63;
    int quad = l >> 4, lr = l & 15;
    int wr = w >> 1, wc = w & 1;

    const bf16* qbase = qkv + (size_t)b * S_ * QKVN + h * DH_;
    const bf16* kbase = qbase + D_;
    const bf16* vbase = vt + (size_t)y * DH_ * S_;

    const int qtA = p, qtB = 31 - p;
    const int nA = p + 1;  // iters for tile A; total 33

    auto stage = [&](int kt, int bi) {
#pragma unroll
        for (int ii = 0; ii < 4; ++ii) {
            int i = 4 * w + ii;
            int row = 4 * i + (l >> 4);
            int cl = (l & 15) ^ (row & 7);
            async_load16(kbase + (size_t)(kt * 64 + row) * QKVN + cl * 8, Ks[bi] + i * 512);
        }
#pragma unroll
        for (int ii = 0; ii < 4; ++ii) {
            int i = 4 * w + ii;
            int dh = 8 * i + (l >> 3);
            int cl = (l & 7) ^ (dh & 7);
            async_load16(vbase + (size_t)dh * S_ + kt * 64 + cl * 8, Vts[bi] + i * 512);
        }
    };

    const float sc2 = 0.12751745f;  // (1/sqrt(128)) * log2(e), folded into Q

    int qt = qtA, q0 = qt * 64;
    bf16x8 qf[2][4];
    auto loadQ = [&]() {
#pragma unroll
        for (int g = 0; g < 2; ++g)
#pragma unroll
            for (int kk = 0; kk < 4; ++kk) {
                bf16x8 raw = *(const bf16x8*)(qbase + (size_t)(q0 + wr * 32 + g * 16 + lr) * QKVN + kk * 32 + quad * 8);
#pragma unroll
                for (int e = 0; e < 8; ++e) qf[g][kk][e] = (bf16)((float)raw[e] * sc2);
            }
    };
    loadQ();

    float L_r[2][4];
    f32x4 o[2][8];
#pragma unroll
    for (int g = 0; g < 2; ++g) {
#pragma unroll
        for (int r = 0; r < 4; ++r) L_r[g][r] = 0.f;
#pragma unroll
        for (int nt = 0; nt < 8; ++nt) o[g][nt] = (f32x4){0.f, 0.f, 0.f, 0.f};
    }

    // combine key-split partials and store ctx rows [q0e, q0e+64)
    auto epilogue = [&](int q0e, int bufe) {
        // per-lane L partials -> per-row partial over this wave's 32 keys
#pragma unroll
        for (int d = 1; d < 16; d <<= 1)
#pragma unroll
            for (int g = 0; g < 2; ++g)
#pragma unroll
                for (int r = 0; r < 4; ++r) L_r[g][r] += __shfl_xor(L_r[g][r], d, 64);
        __syncthreads();  // all waves done reading Ks/Vts[bufe]
        float* slab = (wr == 0) ? (float*)&Ks[bufe][0] : (float*)&Vts[bufe][0];
        int go = 1 - wc;  // half I contribute to partner's output
#pragma unroll
        for (int nt = 0; nt < 8; ++nt)
#pragma unroll
            for (int r = 0; r < 4; ++r)
                slab[wc * 2048 + (quad * 4 + r) * 128 + nt * 16 + lr] = o[go][nt][r];
        if (lr == 0) {
#pragma unroll
            for (int r = 0; r < 4; ++r) Lx[wr][wc][quad * 4 + r] = L_r[go][r];
        }
        __syncthreads();  // partials visible
#pragma unroll
        for (int r = 0; r < 4; ++r) {
            float Lt = L_r[wc][r] + Lx[wr][1 - wc][quad * 4 + r];
            float inv = __builtin_amdgcn_rcpf(Lt);
            int q = q0e + wr * 32 + wc * 16 + quad * 4 + r;
#pragma unroll
            for (int nt = 0; nt < 8; ++nt) {
                float ot = o[wc][nt][r] + slab[(1 - wc) * 2048 + (quad * 4 + r) * 128 + nt * 16 + lr];
                ctx[(size_t)(b * S_ + q) * D_ + h * DH_ + nt * 16 + lr] = (bf16)(ot * inv);
            }
        }
    };

    stage(0, 0);  // prologue

    for (int it = 0; it < 33; ++it) {
        int buf = it & 1;
        asm volatile("s_waitcnt vmcnt(0)" ::: "memory");
        __syncthreads();
        if (it + 1 < 33) {
            int nit = it + 1;
            int nkt = (nit < nA) ? nit : (nit - nA);
            stage(nkt, buf ^ 1);  // in flight across this iter's compute
        }
        int kt = (it < nA) ? it : (it - nA);

        // S = Q K^T: 2 row-groups x this wave's 32 keys; each kf feeds 2 MFMAs
        f32x4 s[2][2];
#pragma unroll
        for (int g = 0; g < 2; ++g)
#pragma unroll
            for (int jt = 0; jt < 2; ++jt) s[g][jt] = (f32x4){0.f, 0.f, 0.f, 0.f};
#pragma unroll
        for (int kk = 0; kk < 4; ++kk)
#pragma unroll
            for (int jt = 0; jt < 2; ++jt) {
                bf16x8 kf = *(const bf16x8*)(Ks[buf] + (wc * 32 + jt * 16 + lr) * 128 + ((4 * kk + quad) ^ (lr & 7)) * 8);
                s[0][jt] = __builtin_amdgcn_mfma_f32_16x16x32_bf16(qf[0][kk], kf, s[0][jt], 0, 0, 0);
                s[1][jt] = __builtin_amdgcn_mfma_f32_16x16x32_bf16(qf[1][kk], kf, s[1][jt], 0, 0, 0);
            }

        // exp2 (m=0) + mask (diag k-tile only) + per-lane L accumulation + P store
        bool diag = (kt == qt);
#pragma unroll
        for (int g = 0; g < 2; ++g) {
#pragma unroll
            for (int jt = 0; jt < 2; ++jt) {
                int keyi = wc * 32 + jt * 16 + lr;
#pragma unroll
                for (int r = 0; r < 4; ++r) {
                    float s2 = s[g][jt][r];
                    if (diag && keyi > wr * 32 + g * 16 + quad * 4 + r) s2 = -3.0e38f;
                    float pv = __builtin_amdgcn_exp2f(s2);
                    s[g][jt][r] = pv;
                    L_r[g][r] += pv;
                }
            }
#pragma unroll
            for (int jt = 0; jt < 2; ++jt)
#pragma unroll
                for (int r = 0; r < 4; ++r)
                    Ps[w][(g * 16 + quad * 4 + r) * 36 + jt * 16 + lr] = (bf16)s[g][jt][r];
        }
        asm volatile("s_waitcnt lgkmcnt(0)" ::: "memory");  // per-wave Ps region

        // O_partial += P(own 32 keys) @ V(own 32-key slice); each vf feeds 2 MFMAs
        bf16x8 pf[2];
#pragma unroll
        for (int g = 0; g < 2; ++g) {
            const bf16* pp = &Ps[w][(g * 16 + lr) * 36 + quad * 8];
            bf16x4 lo = *(const bf16x4*)pp;
            bf16x4 hi = *(const bf16x4*)(pp + 4);
            pf[g] = __builtin_shufflevector(lo, hi, 0, 1, 2, 3, 4, 5, 6, 7);
        }
#pragma unroll
        for (int nt = 0; nt < 8; ++nt) {
            bf16x8 vf = *(const bf16x8*)(Vts[buf] + (nt * 16 + lr) * 64 + ((4 * wc + quad) ^ (lr & 7)) * 8);
            o[0][nt] = __builtin_amdgcn_mfma_f32_16x16x32_bf16(pf[0], vf, o[0][nt], 0, 0, 0);
            o[1][nt] = __builtin_amdgcn_mfma_f32_16x16x32_bf16(pf[1], vf, o[1][nt], 0, 0, 0);
        }

        // tile switch A -> B after A's diagonal iteration
        if (it == nA - 1) {
            epilogue(q0, buf);
            qt = qtB;
            q0 = qt * 64;
            loadQ();
#pragma unroll
            for (int g = 0; g < 2; ++g) {
#pragma unroll
                for (int r = 0; r < 4; ++r) L_r[g][r] = 0.f;
#pragma unroll
                for (int nt = 0; nt < 8; ++nt) o[g][nt] = (f32x4){0.f, 0.f, 0.f, 0.f};
            }
        }
    }

    epilogue(q0, 0);  // tile B (last iter it=32 used buf 0)
}

extern "C" void kernel_launch(void* const* d_in, const int* in_sizes, int n_in,
                              void* d_out, int out_size, void* d_ws, size_t ws_size,
                              hipStream_t stream) {
    const float* x  = (const float*)d_in[0];
    const float* Wq = (const float*)d_in[1];
    const float* Wk = (const float*)d_in[2];
    const float* Wv = (const float*)d_in[3];
    const float* Wo = (const float*)d_in[4];
    float* out = (float*)d_out;

    char* ws = (char*)d_ws;
    bf16* WqkvT = (bf16*)(ws);                       // 3*2048*2048*2 = 25165824
    bf16* WoT   = (bf16*)(ws + 25165824);            // 2048*2048*2   =  8388608
    bf16* qkv   = (bf16*)(ws + 33554432);            // 4096*6144*2   = 50331648
    bf16* vt    = (bf16*)(ws + 83886080);            // 32*128*2048*2 = 16777216
    bf16* ctx   = (bf16*)(ws + 100663296);           // 4096*2048*2   = 16777216
    bf16* xb    = (bf16*)(ws + 117440512);           // 4096*2048*2   = 16777216
    // total ws use: 134217728 bytes (128 MiB)

    prep_kernel<<<8192, 256, 0, stream>>>(x, Wq, Wk, Wv, Wo, xb, WqkvT, WoT);
    gemm_256x128<48, bf16><<<dim3(768), 512, 0, stream>>>(xb, WqkvT, qkv, vt);
    attn_kernel<<<dim3(16, 32), 256, 0, stream>>>(qkv, vt, ctx);
    gemm_256x128<16, float><<<dim3(256), 512, 0, stream>>>(ctx, WoT, out, nullptr);
}

// Round 14
// 360.690 us; speedup vs baseline: 1.4140x; 1.4140x over previous
//
#include <hip/hip_runtime.h>

typedef __bf16 bf16;
typedef __bf16 bf16x4 __attribute__((ext_vector_type(4)));
typedef __bf16 bf16x8 __attribute__((ext_vector_type(8)));
typedef float f32x4 __attribute__((ext_vector_type(4)));

#define B_ 2
#define S_ 2048
#define D_ 2048
#define H_ 16
#define DH_ 128
#define QKVN 6144

__device__ __forceinline__ void async_load16(const bf16* g, bf16* l) {
    __builtin_amdgcn_global_load_lds((const __attribute__((address_space(1))) void*)g,
                                     (__attribute__((address_space(3))) void*)l, 16, 0, 0);
}

__device__ __forceinline__ unsigned int bf16_bits(float x) {
    bf16 h = (bf16)x;
    return (unsigned int)__builtin_bit_cast(unsigned short, h);
}

// ======== merged prep: x cast (blocks 0..4095) + 4x weight transpose (4096..8191) =
__global__ __launch_bounds__(256) void prep_kernel(const float* __restrict__ x,
                                                   const float* __restrict__ Wq,
                                                   const float* __restrict__ Wk,
                                                   const float* __restrict__ Wv,
                                                   const float* __restrict__ Wo,
                                                   bf16* __restrict__ xb,
                                                   bf16* __restrict__ WqkvT,
                                                   bf16* __restrict__ WoT) {
    __shared__ unsigned int tile[64][65];  // used by wtrans half only
    int bid = blockIdx.x;
    int t = threadIdx.x;
    if (bid < 4096) {
        // ---- cvt: f32 -> bf16, 8 elems/thread ----
        size_t i = (size_t)bid * 256 + t;
        const float4* s = (const float4*)x;
        float4 a = s[2 * i], b = s[2 * i + 1];
        bf16x8 o;
        o[0] = (bf16)a.x; o[1] = (bf16)a.y; o[2] = (bf16)a.z; o[3] = (bf16)a.w;
        o[4] = (bf16)b.x; o[5] = (bf16)b.y; o[6] = (bf16)b.z; o[7] = (bf16)b.w;
        *(bf16x8*)(xb + 8 * i) = o;
        return;
    }
    // ---- wtrans: W[K][N] f32 -> Wt[N][K] bf16, 4 matrices ----
    int rbid = bid - 4096;             // 0..4095
    int z = rbid >> 10;                // matrix id
    int by = (rbid >> 5) & 31, bx = rbid & 31;
    const float* src = (z == 0) ? Wq : (z == 1) ? Wk : (z == 2) ? Wv : Wo;
    bf16* dst = (z < 3) ? (WqkvT + (size_t)z * D_ * D_) : WoT;
    int r0 = by * 64, c0 = bx * 64;
    int tr = t >> 4, tc4 = (t & 15) * 4;
#pragma unroll
    for (int it = 0; it < 4; ++it) {
        int r = it * 16 + tr;
        float4 v = *(const float4*)(src + (size_t)(r0 + r) * D_ + c0 + tc4);
        tile[r][tc4 + 0] = bf16_bits(v.x);
        tile[r][tc4 + 1] = bf16_bits(v.y);
        tile[r][tc4 + 2] = bf16_bits(v.z);
        tile[r][tc4 + 3] = bf16_bits(v.w);
    }
    __syncthreads();
#pragma unroll
    for (int it = 0; it < 4; ++it) {
        int a = it * 16 + tr;
        unsigned u0 = tile[tc4 + 0][a], u1 = tile[tc4 + 1][a];
        unsigned u2 = tile[tc4 + 2][a], u3 = tile[tc4 + 3][a];
        uint2 v;
        v.x = (u0 & 0xffffu) | (u1 << 16);
        v.y = (u2 & 0xffffu) | (u3 << 16);
        *(uint2*)(dst + (size_t)(c0 + a) * D_ + r0 + tc4) = v;
    }
}

// ========== shared pieces for 256x128-tile GEMMs ==================================
#define QK_K 2048
#define QK_N 6144

__device__ __forceinline__ bf16x8 lds_frag(const bf16* tile, int row, int colByte) {
    int off = row * 128 + (colByte ^ ((row & 7) << 4));
    return *(const bf16x8*)((const char*)tile + off);
}

template <int MH>
__device__ __forceinline__ void mmaq16(f32x4 (&acc)[8][2], const bf16x8 (&afr)[4][2],
                                       const bf16x8 (&bf)[2][2]) {
    __builtin_amdgcn_s_setprio(1);
#pragma unroll
    for (int i = 0; i < 4; ++i)
#pragma unroll
        for (int j = 0; j < 2; ++j)
#pragma unroll
            for (int kk = 0; kk < 2; ++kk)
                acc[MH * 4 + i][j] = __builtin_amdgcn_mfma_f32_16x16x32_bf16(
                    afr[i][kk], bf[j][kk], acc[MH * 4 + i][j], 0, 0, 0);
    __builtin_amdgcn_s_setprio(0);
}

// ========== 256x128-tile GEMM (r7 schedule, FROZEN), templated on N/out-type ======
// V panels (NPAN=48, n0>=4096) write transposed vt[bh][dh][s] via LDS bounce
// (r12: coalesced 512B rows).
template <int NPAN, typename CT>
__global__ __launch_bounds__(512, 2) void gemm_256x128(const bf16* __restrict__ A,
                                                       const bf16* __restrict__ Bt,
                                                       CT* __restrict__ C,
                                                       bf16* __restrict__ VT) {
    __shared__ __align__(16) bf16 As[3][256 * 64];  // 96 KB
    __shared__ __align__(16) bf16 Bs[3][128 * 64];  // 48 KB

    const int NN = NPAN * 128;
    int t = threadIdx.x;
    int wid = t >> 6, lane = t & 63;
    int quad = lane >> 4, lr = lane & 15;
    int wr = wid >> 2, wn = wid & 3;  // 2 (M) x 4 (N) wave grid

    int bid = blockIdx.x;
    int swz = (bid & 7) * (2 * NPAN) + (bid >> 3);  // 16*NPAN/8 per XCD
    int tn = swz >> 4, tm = swz & 15;
    size_t m0 = (size_t)tm * 256, n0 = (size_t)tn * 128;

    int row_r[2], c8s_r[2];
#pragma unroll
    for (int r = 0; r < 2; ++r) {
        int idx = r * 512 + t;
        row_r[r] = idx >> 3;
        c8s_r[r] = (idx & 7) ^ (row_r[r] & 7);
    }

    auto stA = [&](int kt, int bufi, int h) {
#pragma unroll
        for (int r = 0; r < 2; ++r)
            async_load16(A + (m0 + h * 128 + row_r[r]) * (size_t)QK_K + kt * 64 + c8s_r[r] * 8,
                         &As[bufi][(h * 1024 + r * 512 + wid * 64) * 8]);
    };
    auto stB = [&](int kt, int bufi) {
#pragma unroll
        for (int r = 0; r < 2; ++r)
            async_load16(Bt + (n0 + row_r[r]) * (size_t)QK_K + kt * 64 + c8s_r[r] * 8,
                         &Bs[bufi][(r * 512 + wid * 64) * 8]);
    };

    f32x4 acc[8][2];
#pragma unroll
    for (int i = 0; i < 8; ++i)
#pragma unroll
        for (int j = 0; j < 2; ++j) acc[i][j] = (f32x4){0.f, 0.f, 0.f, 0.f};

    bf16x8 afr[4][2], bf[2][2];

    auto readA = [&](int bufi, int mh) {
#pragma unroll
        for (int i = 0; i < 4; ++i)
#pragma unroll
            for (int kk = 0; kk < 2; ++kk)
                afr[i][kk] = lds_frag(As[bufi], mh * 128 + wr * 64 + i * 16 + lr, kk * 64 + quad * 16);
    };
    auto readB = [&](int bufi) {
#pragma unroll
        for (int j = 0; j < 2; ++j)
#pragma unroll
            for (int kk = 0; kk < 2; ++kk)
                bf[j][kk] = lds_frag(Bs[bufi], wn * 32 + j * 16 + lr, kk * 64 + quad * 16);
    };

    stB(0, 0); stA(0, 0, 0); stA(0, 0, 1);
    stB(1, 1); stA(1, 1, 0); stA(1, 1, 1);
    asm volatile("s_waitcnt vmcnt(8)" ::: "memory");
    __builtin_amdgcn_s_barrier();

    auto tile2ph = [&](int kt, int cb, int nb2) {
        readA(cb, 0);
        readB(cb);
        stB(kt + 2, nb2);
        stA(kt + 2, nb2, 0);
        __builtin_amdgcn_s_barrier();
        asm volatile("s_waitcnt lgkmcnt(0)" ::: "memory");
        __builtin_amdgcn_sched_barrier(0);
        mmaq16<0>(acc, afr, bf);
        asm volatile("s_waitcnt vmcnt(10)" ::: "memory");
        __builtin_amdgcn_s_barrier();
        readA(cb, 1);
        stA(kt + 2, nb2, 1);
        __builtin_amdgcn_s_barrier();
        asm volatile("s_waitcnt lgkmcnt(0)" ::: "memory");
        __builtin_amdgcn_sched_barrier(0);
        mmaq16<1>(acc, afr, bf);
        asm volatile("s_waitcnt vmcnt(8)" ::: "memory");
        __builtin_amdgcn_s_barrier();
    };

    for (int kt3 = 0; kt3 < 30; kt3 += 3) {
        tile2ph(kt3 + 0, 0, 2);
        tile2ph(kt3 + 1, 1, 0);
        tile2ph(kt3 + 2, 2, 1);
    }

    {  // tail: tiles 30 (buf0) and 31 (buf1)
        readA(0, 0);
        readB(0);
        __builtin_amdgcn_s_barrier();
        asm volatile("s_waitcnt lgkmcnt(0)" ::: "memory");
        __builtin_amdgcn_sched_barrier(0);
        mmaq16<0>(acc, afr, bf);
        asm volatile("s_waitcnt vmcnt(6)" ::: "memory");
        __builtin_amdgcn_s_barrier();
        readA(0, 1);
        __builtin_amdgcn_s_barrier();
        asm volatile("s_waitcnt lgkmcnt(0)" ::: "memory");
        __builtin_amdgcn_sched_barrier(0);
        mmaq16<1>(acc, afr, bf);
        asm volatile("s_waitcnt vmcnt(2)" ::: "memory");
        __builtin_amdgcn_s_barrier();
        readA(1, 0);
        readB(1);
        __builtin_amdgcn_s_barrier();
        asm volatile("s_waitcnt lgkmcnt(0)" ::: "memory");
        __builtin_amdgcn_sched_barrier(0);
        mmaq16<0>(acc, afr, bf);
        asm volatile("s_waitcnt vmcnt(0)" ::: "memory");
        __builtin_amdgcn_s_barrier();
        readA(1, 1);
        asm volatile("s_waitcnt lgkmcnt(0)" ::: "memory");
        __builtin_amdgcn_sched_barrier(0);
        mmaq16<1>(acc, afr, bf);
    }

    if constexpr (NPAN == 48) {
        if (n0 >= 4096) {
            // V panel: transpose via LDS bounce (As is dead), then coalesced store.
            int h = (int)((n0 - 4096) >> 7);
            size_t b = m0 >> 11;
            size_t s0 = m0 & 2047;
            bf16* vtb = VT + (b * 16 + h) * (size_t)(DH_ * S_);
            bf16* vl = &As[0][0];       // [128][264] padded: 67584 B <= 98304 B
            const int SP = 264;
            __builtin_amdgcn_s_barrier();
#pragma unroll
            for (int mh = 0; mh < 2; ++mh)
#pragma unroll
                for (int i = 0; i < 4; ++i)
#pragma unroll
                    for (int j = 0; j < 2; ++j) {
                        int dh = wn * 32 + j * 16 + lr;
                        int sl = mh * 128 + wr * 64 + i * 16 + quad * 4;
                        bf16x4 pk;
#pragma unroll
                        for (int r = 0; r < 4; ++r) pk[r] = (bf16)acc[mh * 4 + i][j][r];
                        *(bf16x4*)(vl + dh * SP + sl) = pk;
                    }
            __builtin_amdgcn_s_barrier();
#pragma unroll
            for (int pass = 0; pass < 8; ++pass) {
                int dh = pass * 16 + (t >> 5);
                int si = (t & 31) * 8;
                bf16x8 v = *(const bf16x8*)(vl + dh * SP + si);
                *(bf16x8*)(vtb + (size_t)dh * S_ + s0 + si) = v;
            }
            return;
        }
    }

#pragma unroll
    for (int mh = 0; mh < 2; ++mh)
#pragma unroll
        for (int i = 0; i < 4; ++i)
#pragma unroll
            for (int j = 0; j < 2; ++j)
#pragma unroll
                for (int r = 0; r < 4; ++r) {
                    size_t row = m0 + mh * 128 + wr * 64 + i * 16 + quad * 4 + r;
                    size_t col = n0 + wn * 32 + j * 16 + lr;
                    C[row * (size_t)NN + col] = (CT)acc[mh * 4 + i][j][r];
                }
}

// ---------------- flash attention, causal (r14: key-split, static-index fix) ------
// r13's key-split regressed 217us: epilogue indexed o[]/L_r[] with RUNTIME go/wc
// -> rule #20: whole accumulator array homed in scratch -> ~2GB HBM scratch
// traffic (WRITE_SIZE 1.1GB measured). r14: wc is wave-uniform, so all
// accumulator accesses go through if(wc==0)/else branches with COMPILE-TIME
// indices; o stays in VGPRs. Combine logic itself unchanged (passed refcheck).
__global__ __launch_bounds__(256, 2) void attn_kernel(const bf16* __restrict__ qkv,
                                                      const bf16* __restrict__ vt,
                                                      bf16* __restrict__ ctx) {
    __shared__ __align__(16) bf16 Ks[2][64 * 128];    // [key][16B-chunk c ^ (key&7)]
    __shared__ __align__(16) bf16 Vts[2][128 * 64];   // [dh][16B-chunk c ^ (dh&7)]
    __shared__ __align__(16) bf16 Ps[4][32 * 36];     // per-wave P [32q][32k], pad 4
    __shared__ float Lx[2][2][16];

    int flat = blockIdx.y * 16 + blockIdx.x;
    int sid = (flat & 7) * 64 + (flat >> 3);
    int y = sid >> 4;
    int p = sid & 15;
    int b = y >> 4, h = y & 15;
    int t = threadIdx.x, w = t >> 6, l = t & 63;
    int quad = l >> 4, lr = l & 15;
    int wr = w >> 1, wc = w & 1;

    const bf16* qbase = qkv + (size_t)b * S_ * QKVN + h * DH_;
    const bf16* kbase = qbase + D_;
    const bf16* vbase = vt + (size_t)y * DH_ * S_;

    const int qtA = p, qtB = 31 - p;
    const int nA = p + 1;  // iters for tile A; total 33

    auto stage = [&](int kt, int bi) {
#pragma unroll
        for (int ii = 0; ii < 4; ++ii) {
            int i = 4 * w + ii;
            int row = 4 * i + (l >> 4);
            int cl = (l & 15) ^ (row & 7);
            async_load16(kbase + (size_t)(kt * 64 + row) * QKVN + cl * 8, Ks[bi] + i * 512);
        }
#pragma unroll
        for (int ii = 0; ii < 4; ++ii) {
            int i = 4 * w + ii;
            int dh = 8 * i + (l >> 3);
            int cl = (l & 7) ^ (dh & 7);
            async_load16(vbase + (size_t)dh * S_ + kt * 64 + cl * 8, Vts[bi] + i * 512);
        }
    };

    const float sc2 = 0.12751745f;  // (1/sqrt(128)) * log2(e), folded into Q

    int qt = qtA, q0 = qt * 64;
    bf16x8 qf[2][4];
    auto loadQ = [&]() {
#pragma unroll
        for (int g = 0; g < 2; ++g)
#pragma unroll
            for (int kk = 0; kk < 4; ++kk) {
                bf16x8 raw = *(const bf16x8*)(qbase + (size_t)(q0 + wr * 32 + g * 16 + lr) * QKVN + kk * 32 + quad * 8);
#pragma unroll
                for (int e = 0; e < 8; ++e) qf[g][kk][e] = (bf16)((float)raw[e] * sc2);
            }
    };
    loadQ();

    float L_r[2][4];
    f32x4 o[2][8];
#pragma unroll
    for (int g = 0; g < 2; ++g) {
#pragma unroll
        for (int r = 0; r < 4; ++r) L_r[g][r] = 0.f;
#pragma unroll
        for (int nt = 0; nt < 8; ++nt) o[g][nt] = (f32x4){0.f, 0.f, 0.f, 0.f};
    }

    // combine key-split partials and store ctx rows [q0e, q0e+64).
    // All o[]/L_r[] indices are compile-time constants (wave-uniform branches).
    auto epilogue = [&](int q0e, int bufe) {
#pragma unroll
        for (int d = 1; d < 16; d <<= 1)
#pragma unroll
            for (int g = 0; g < 2; ++g)
#pragma unroll
                for (int r = 0; r < 4; ++r) L_r[g][r] += __shfl_xor(L_r[g][r], d, 64);
        __syncthreads();  // all waves done reading Ks/Vts[bufe]
        float* slab = (wr == 0) ? (float*)&Ks[bufe][0] : (float*)&Vts[bufe][0];
        if (wc == 0) {
            // contribute row-group 1 partial to partner; region index = own wc = 0
#pragma unroll
            for (int nt = 0; nt < 8; ++nt)
#pragma unroll
                for (int r = 0; r < 4; ++r)
                    slab[(quad * 4 + r) * 128 + nt * 16 + lr] = o[1][nt][r];
            if (lr == 0) {
#pragma unroll
                for (int r = 0; r < 4; ++r) Lx[wr][0][quad * 4 + r] = L_r[1][r];
            }
        } else {
#pragma unroll
            for (int nt = 0; nt < 8; ++nt)
#pragma unroll
                for (int r = 0; r < 4; ++r)
                    slab[2048 + (quad * 4 + r) * 128 + nt * 16 + lr] = o[0][nt][r];
            if (lr == 0) {
#pragma unroll
                for (int r = 0; r < 4; ++r) Lx[wr][1][quad * 4 + r] = L_r[0][r];
            }
        }
        __syncthreads();  // partials visible
        if (wc == 0) {
            // output row-group 0; partner's (wr,1) contribution in region 1
#pragma unroll
            for (int r = 0; r < 4; ++r) {
                float Lt = L_r[0][r] + Lx[wr][1][quad * 4 + r];
                float inv = __builtin_amdgcn_rcpf(Lt);
                int q = q0e + wr * 32 + quad * 4 + r;
#pragma unroll
                for (int nt = 0; nt < 8; ++nt) {
                    float ot = o[0][nt][r] + slab[2048 + (quad * 4 + r) * 128 + nt * 16 + lr];
                    ctx[(size_t)(b * S_ + q) * D_ + h * DH_ + nt * 16 + lr] = (bf16)(ot * inv);
                }
            }
        } else {
            // output row-group 1; partner's (wr,0) contribution in region 0
#pragma unroll
            for (int r = 0; r < 4; ++r) {
                float Lt = L_r[1][r] + Lx[wr][0][quad * 4 + r];
                float inv = __builtin_amdgcn_rcpf(Lt);
                int q = q0e + wr * 32 + 16 + quad * 4 + r;
#pragma unroll
                for (int nt = 0; nt < 8; ++nt) {
                    float ot = o[1][nt][r] + slab[(quad * 4 + r) * 128 + nt * 16 + lr];
                    ctx[(size_t)(b * S_ + q) * D_ + h * DH_ + nt * 16 + lr] = (bf16)(ot * inv);
                }
            }
        }
    };

    stage(0, 0);  // prologue

    for (int it = 0; it < 33; ++it) {
        int buf = it & 1;
        asm volatile("s_waitcnt vmcnt(0)" ::: "memory");
        __syncthreads();
        if (it + 1 < 33) {
            int nit = it + 1;
            int nkt = (nit < nA) ? nit : (nit - nA);
            stage(nkt, buf ^ 1);  // in flight across this iter's compute
        }
        int kt = (it < nA) ? it : (it - nA);

        // S = Q K^T: 2 row-groups x this wave's 32 keys; each kf feeds 2 MFMAs
        f32x4 s[2][2];
#pragma unroll
        for (int g = 0; g < 2; ++g)
#pragma unroll
            for (int jt = 0; jt < 2; ++jt) s[g][jt] = (f32x4){0.f, 0.f, 0.f, 0.f};
#pragma unroll
        for (int kk = 0; kk < 4; ++kk)
#pragma unroll
            for (int jt = 0; jt < 2; ++jt) {
                bf16x8 kf = *(const bf16x8*)(Ks[buf] + (wc * 32 + jt * 16 + lr) * 128 + ((4 * kk + quad) ^ (lr & 7)) * 8);
                s[0][jt] = __builtin_amdgcn_mfma_f32_16x16x32_bf16(qf[0][kk], kf, s[0][jt], 0, 0, 0);
                s[1][jt] = __builtin_amdgcn_mfma_f32_16x16x32_bf16(qf[1][kk], kf, s[1][jt], 0, 0, 0);
            }

        // exp2 (m=0) + mask (diag k-tile only) + per-lane L accumulation + P store
        bool diag = (kt == qt);
#pragma unroll
        for (int g = 0; g < 2; ++g) {
#pragma unroll
            for (int jt = 0; jt < 2; ++jt) {
                int keyi = wc * 32 + jt * 16 + lr;
#pragma unroll
                for (int r = 0; r < 4; ++r) {
                    float s2 = s[g][jt][r];
                    if (diag && keyi > wr * 32 + g * 16 + quad * 4 + r) s2 = -3.0e38f;
                    float pv = __builtin_amdgcn_exp2f(s2);
                    s[g][jt][r] = pv;
                    L_r[g][r] += pv;
                }
            }
#pragma unroll
            for (int jt = 0; jt < 2; ++jt)
#pragma unroll
                for (int r = 0; r < 4; ++r)
                    Ps[w][(g * 16 + quad * 4 + r) * 36 + jt * 16 + lr] = (bf16)s[g][jt][r];
        }
        asm volatile("s_waitcnt lgkmcnt(0)" ::: "memory");  // per-wave Ps region

        // O_partial += P(own 32 keys) @ V(own 32-key slice); each vf feeds 2 MFMAs
        bf16x8 pf[2];
#pragma unroll
        for (int g = 0; g < 2; ++g) {
            const bf16* pp = &Ps[w][(g * 16 + lr) * 36 + quad * 8];
            bf16x4 lo = *(const bf16x4*)pp;
            bf16x4 hi = *(const bf16x4*)(pp + 4);
            pf[g] = __builtin_shufflevector(lo, hi, 0, 1, 2, 3, 4, 5, 6, 7);
        }
#pragma unroll
        for (int nt = 0; nt < 8; ++nt) {
            bf16x8 vf = *(const bf16x8*)(Vts[buf] + (nt * 16 + lr) * 64 + ((4 * wc + quad) ^ (lr & 7)) * 8);
            o[0][nt] = __builtin_amdgcn_mfma_f32_16x16x32_bf16(pf[0], vf, o[0][nt], 0, 0, 0);
            o[1][nt] = __builtin_amdgcn_mfma_f32_16x16x32_bf16(pf[1], vf, o[1][nt], 0, 0, 0);
        }

        // tile switch A -> B after A's diagonal iteration
        if (it == nA - 1) {
            epilogue(q0, buf);
            qt = qtB;
            q0 = qt * 64;
            loadQ();
#pragma unroll
            for (int g = 0; g < 2; ++g) {
#pragma unroll
                for (int r = 0; r < 4; ++r) L_r[g][r] = 0.f;
#pragma unroll
                for (int nt = 0; nt < 8; ++nt) o[g][nt] = (f32x4){0.f, 0.f, 0.f, 0.f};
            }
        }
    }

    epilogue(q0, 0);  // tile B (last iter it=32 used buf 0)
}

extern "C" void kernel_launch(void* const* d_in, const int* in_sizes, int n_in,
                              void* d_out, int out_size, void* d_ws, size_t ws_size,
                              hipStream_t stream) {
    const float* x  = (const float*)d_in[0];
    const float* Wq = (const float*)d_in[1];
    const float* Wk = (const float*)d_in[2];
    const float* Wv = (const float*)d_in[3];
    const float* Wo = (const float*)d_in[4];
    float* out = (float*)d_out;

    char* ws = (char*)d_ws;
    bf16* WqkvT = (bf16*)(ws);                       // 3*2048*2048*2 = 25165824
    bf16* WoT   = (bf16*)(ws + 25165824);            // 2048*2048*2   =  8388608
    bf16* qkv   = (bf16*)(ws + 33554432);            // 4096*6144*2   = 50331648
    bf16* vt    = (bf16*)(ws + 83886080);            // 32*128*2048*2 = 16777216
    bf16* ctx   = (bf16*)(ws + 100663296);           // 4096*2048*2   = 16777216
    bf16* xb    = (bf16*)(ws + 117440512);           // 4096*2048*2   = 16777216
    // total ws use: 134217728 bytes (128 MiB)

    prep_kernel<<<8192, 256, 0, stream>>>(x, Wq, Wk, Wv, Wo, xb, WqkvT, WoT);
    gemm_256x128<48, bf16><<<dim3(768), 512, 0, stream>>>(xb, WqkvT, qkv, vt);
    attn_kernel<<<dim3(16, 32), 256, 0, stream>>>(qkv, vt, ctx);
    gemm_256x128<16, float><<<dim3(256), 512, 0, stream>>>(ctx, WoT, out, nullptr);
}

// Round 15
// 354.038 us; speedup vs baseline: 1.4406x; 1.0188x over previous
//
#include <hip/hip_runtime.h>

typedef __bf16 bf16;
typedef __bf16 bf16x4 __attribute__((ext_vector_type(4)));
typedef __bf16 bf16x8 __attribute__((ext_vector_type(8)));
typedef float f32x4 __attribute__((ext_vector_type(4)));

#define B_ 2
#define S_ 2048
#define D_ 2048
#define H_ 16
#define DH_ 128
#define QKVN 6144

__device__ __forceinline__ void async_load16(const bf16* g, bf16* l) {
    __builtin_amdgcn_global_load_lds((const __attribute__((address_space(1))) void*)g,
                                     (__attribute__((address_space(3))) void*)l, 16, 0, 0);
}

__device__ __forceinline__ unsigned int bf16_bits(float x) {
    bf16 h = (bf16)x;
    return (unsigned int)__builtin_bit_cast(unsigned short, h);
}

// ======== merged prep: x cast (blocks 0..4095) + 4x weight transpose (4096..8191) =
__global__ __launch_bounds__(256) void prep_kernel(const float* __restrict__ x,
                                                   const float* __restrict__ Wq,
                                                   const float* __restrict__ Wk,
                                                   const float* __restrict__ Wv,
                                                   const float* __restrict__ Wo,
                                                   bf16* __restrict__ xb,
                                                   bf16* __restrict__ WqkvT,
                                                   bf16* __restrict__ WoT) {
    __shared__ unsigned int tile[64][65];  // used by wtrans half only
    int bid = blockIdx.x;
    int t = threadIdx.x;
    if (bid < 4096) {
        // ---- cvt: f32 -> bf16, 8 elems/thread ----
        size_t i = (size_t)bid * 256 + t;
        const float4* s = (const float4*)x;
        float4 a = s[2 * i], b = s[2 * i + 1];
        bf16x8 o;
        o[0] = (bf16)a.x; o[1] = (bf16)a.y; o[2] = (bf16)a.z; o[3] = (bf16)a.w;
        o[4] = (bf16)b.x; o[5] = (bf16)b.y; o[6] = (bf16)b.z; o[7] = (bf16)b.w;
        *(bf16x8*)(xb + 8 * i) = o;
        return;
    }
    // ---- wtrans: W[K][N] f32 -> Wt[N][K] bf16, 4 matrices ----
    int rbid = bid - 4096;             // 0..4095
    int z = rbid >> 10;                // matrix id
    int by = (rbid >> 5) & 31, bx = rbid & 31;
    const float* src = (z == 0) ? Wq : (z == 1) ? Wk : (z == 2) ? Wv : Wo;
    bf16* dst = (z < 3) ? (WqkvT + (size_t)z * D_ * D_) : WoT;
    int r0 = by * 64, c0 = bx * 64;
    int tr = t >> 4, tc4 = (t & 15) * 4;
#pragma unroll
    for (int it = 0; it < 4; ++it) {
        int r = it * 16 + tr;
        float4 v = *(const float4*)(src + (size_t)(r0 + r) * D_ + c0 + tc4);
        tile[r][tc4 + 0] = bf16_bits(v.x);
        tile[r][tc4 + 1] = bf16_bits(v.y);
        tile[r][tc4 + 2] = bf16_bits(v.z);
        tile[r][tc4 + 3] = bf16_bits(v.w);
    }
    __syncthreads();
#pragma unroll
    for (int it = 0; it < 4; ++it) {
        int a = it * 16 + tr;
        unsigned u0 = tile[tc4 + 0][a], u1 = tile[tc4 + 1][a];
        unsigned u2 = tile[tc4 + 2][a], u3 = tile[tc4 + 3][a];
        uint2 v;
        v.x = (u0 & 0xffffu) | (u1 << 16);
        v.y = (u2 & 0xffffu) | (u3 << 16);
        *(uint2*)(dst + (size_t)(c0 + a) * D_ + r0 + tc4) = v;
    }
}

// ========== shared pieces for 256x128-tile GEMMs ==================================
#define QK_K 2048
#define QK_N 6144

__device__ __forceinline__ bf16x8 lds_frag(const bf16* tile, int row, int colByte) {
    int off = row * 128 + (colByte ^ ((row & 7) << 4));
    return *(const bf16x8*)((const char*)tile + off);
}

template <int MH>
__device__ __forceinline__ void mmaq16(f32x4 (&acc)[8][2], const bf16x8 (&afr)[4][2],
                                       const bf16x8 (&bf)[2][2]) {
    __builtin_amdgcn_s_setprio(1);
#pragma unroll
    for (int i = 0; i < 4; ++i)
#pragma unroll
        for (int j = 0; j < 2; ++j)
#pragma unroll
            for (int kk = 0; kk < 2; ++kk)
                acc[MH * 4 + i][j] = __builtin_amdgcn_mfma_f32_16x16x32_bf16(
                    afr[i][kk], bf[j][kk], acc[MH * 4 + i][j], 0, 0, 0);
    __builtin_amdgcn_s_setprio(0);
}

// ========== 256x128-tile GEMM (r7 schedule, FROZEN), templated on N/out-type ======
// V panels (NPAN=48, n0>=4096) write transposed vt[bh][dh][s] via LDS bounce
// (r12: coalesced 512B rows).
template <int NPAN, typename CT>
__global__ __launch_bounds__(512, 2) void gemm_256x128(const bf16* __restrict__ A,
                                                       const bf16* __restrict__ Bt,
                                                       CT* __restrict__ C,
                                                       bf16* __restrict__ VT) {
    __shared__ __align__(16) bf16 As[3][256 * 64];  // 96 KB
    __shared__ __align__(16) bf16 Bs[3][128 * 64];  // 48 KB

    const int NN = NPAN * 128;
    int t = threadIdx.x;
    int wid = t >> 6, lane = t & 63;
    int quad = lane >> 4, lr = lane & 15;
    int wr = wid >> 2, wn = wid & 3;  // 2 (M) x 4 (N) wave grid

    int bid = blockIdx.x;
    int swz = (bid & 7) * (2 * NPAN) + (bid >> 3);  // 16*NPAN/8 per XCD
    int tn = swz >> 4, tm = swz & 15;
    size_t m0 = (size_t)tm * 256, n0 = (size_t)tn * 128;

    int row_r[2], c8s_r[2];
#pragma unroll
    for (int r = 0; r < 2; ++r) {
        int idx = r * 512 + t;
        row_r[r] = idx >> 3;
        c8s_r[r] = (idx & 7) ^ (row_r[r] & 7);
    }

    auto stA = [&](int kt, int bufi, int h) {
#pragma unroll
        for (int r = 0; r < 2; ++r)
            async_load16(A + (m0 + h * 128 + row_r[r]) * (size_t)QK_K + kt * 64 + c8s_r[r] * 8,
                         &As[bufi][(h * 1024 + r * 512 + wid * 64) * 8]);
    };
    auto stB = [&](int kt, int bufi) {
#pragma unroll
        for (int r = 0; r < 2; ++r)
            async_load16(Bt + (n0 + row_r[r]) * (size_t)QK_K + kt * 64 + c8s_r[r] * 8,
                         &Bs[bufi][(r * 512 + wid * 64) * 8]);
    };

    f32x4 acc[8][2];
#pragma unroll
    for (int i = 0; i < 8; ++i)
#pragma unroll
        for (int j = 0; j < 2; ++j) acc[i][j] = (f32x4){0.f, 0.f, 0.f, 0.f};

    bf16x8 afr[4][2], bf[2][2];

    auto readA = [&](int bufi, int mh) {
#pragma unroll
        for (int i = 0; i < 4; ++i)
#pragma unroll
            for (int kk = 0; kk < 2; ++kk)
                afr[i][kk] = lds_frag(As[bufi], mh * 128 + wr * 64 + i * 16 + lr, kk * 64 + quad * 16);
    };
    auto readB = [&](int bufi) {
#pragma unroll
        for (int j = 0; j < 2; ++j)
#pragma unroll
            for (int kk = 0; kk < 2; ++kk)
                bf[j][kk] = lds_frag(Bs[bufi], wn * 32 + j * 16 + lr, kk * 64 + quad * 16);
    };

    stB(0, 0); stA(0, 0, 0); stA(0, 0, 1);
    stB(1, 1); stA(1, 1, 0); stA(1, 1, 1);
    asm volatile("s_waitcnt vmcnt(8)" ::: "memory");
    __builtin_amdgcn_s_barrier();

    auto tile2ph = [&](int kt, int cb, int nb2) {
        readA(cb, 0);
        readB(cb);
        stB(kt + 2, nb2);
        stA(kt + 2, nb2, 0);
        __builtin_amdgcn_s_barrier();
        asm volatile("s_waitcnt lgkmcnt(0)" ::: "memory");
        __builtin_amdgcn_sched_barrier(0);
        mmaq16<0>(acc, afr, bf);
        asm volatile("s_waitcnt vmcnt(10)" ::: "memory");
        __builtin_amdgcn_s_barrier();
        readA(cb, 1);
        stA(kt + 2, nb2, 1);
        __builtin_amdgcn_s_barrier();
        asm volatile("s_waitcnt lgkmcnt(0)" ::: "memory");
        __builtin_amdgcn_sched_barrier(0);
        mmaq16<1>(acc, afr, bf);
        asm volatile("s_waitcnt vmcnt(8)" ::: "memory");
        __builtin_amdgcn_s_barrier();
    };

    for (int kt3 = 0; kt3 < 30; kt3 += 3) {
        tile2ph(kt3 + 0, 0, 2);
        tile2ph(kt3 + 1, 1, 0);
        tile2ph(kt3 + 2, 2, 1);
    }

    {  // tail: tiles 30 (buf0) and 31 (buf1)
        readA(0, 0);
        readB(0);
        __builtin_amdgcn_s_barrier();
        asm volatile("s_waitcnt lgkmcnt(0)" ::: "memory");
        __builtin_amdgcn_sched_barrier(0);
        mmaq16<0>(acc, afr, bf);
        asm volatile("s_waitcnt vmcnt(6)" ::: "memory");
        __builtin_amdgcn_s_barrier();
        readA(0, 1);
        __builtin_amdgcn_s_barrier();
        asm volatile("s_waitcnt lgkmcnt(0)" ::: "memory");
        __builtin_amdgcn_sched_barrier(0);
        mmaq16<1>(acc, afr, bf);
        asm volatile("s_waitcnt vmcnt(2)" ::: "memory");
        __builtin_amdgcn_s_barrier();
        readA(1, 0);
        readB(1);
        __builtin_amdgcn_s_barrier();
        asm volatile("s_waitcnt lgkmcnt(0)" ::: "memory");
        __builtin_amdgcn_sched_barrier(0);
        mmaq16<0>(acc, afr, bf);
        asm volatile("s_waitcnt vmcnt(0)" ::: "memory");
        __builtin_amdgcn_s_barrier();
        readA(1, 1);
        asm volatile("s_waitcnt lgkmcnt(0)" ::: "memory");
        __builtin_amdgcn_sched_barrier(0);
        mmaq16<1>(acc, afr, bf);
    }

    if constexpr (NPAN == 48) {
        if (n0 >= 4096) {
            // V panel: transpose via LDS bounce (As is dead), then coalesced store.
            int h = (int)((n0 - 4096) >> 7);
            size_t b = m0 >> 11;
            size_t s0 = m0 & 2047;
            bf16* vtb = VT + (b * 16 + h) * (size_t)(DH_ * S_);
            bf16* vl = &As[0][0];       // [128][264] padded: 67584 B <= 98304 B
            const int SP = 264;
            __builtin_amdgcn_s_barrier();
#pragma unroll
            for (int mh = 0; mh < 2; ++mh)
#pragma unroll
                for (int i = 0; i < 4; ++i)
#pragma unroll
                    for (int j = 0; j < 2; ++j) {
                        int dh = wn * 32 + j * 16 + lr;
                        int sl = mh * 128 + wr * 64 + i * 16 + quad * 4;
                        bf16x4 pk;
#pragma unroll
                        for (int r = 0; r < 4; ++r) pk[r] = (bf16)acc[mh * 4 + i][j][r];
                        *(bf16x4*)(vl + dh * SP + sl) = pk;
                    }
            __builtin_amdgcn_s_barrier();
#pragma unroll
            for (int pass = 0; pass < 8; ++pass) {
                int dh = pass * 16 + (t >> 5);
                int si = (t & 31) * 8;
                bf16x8 v = *(const bf16x8*)(vl + dh * SP + si);
                *(bf16x8*)(vtb + (size_t)dh * S_ + s0 + si) = v;
            }
            return;
        }
    }

#pragma unroll
    for (int mh = 0; mh < 2; ++mh)
#pragma unroll
        for (int i = 0; i < 4; ++i)
#pragma unroll
            for (int j = 0; j < 2; ++j)
#pragma unroll
                for (int r = 0; r < 4; ++r) {
                    size_t row = m0 + mh * 128 + wr * 64 + i * 16 + quad * 4 + r;
                    size_t col = n0 + wn * 32 + j * 16 + lr;
                    C[row * (size_t)NN + col] = (CT)acc[mh * 4 + i][j][r];
                }
}

// ---------------- flash attention, causal (r12 version RESTORED + T5 setprio) -----
// r13/r14 key-split experiment closed: halving LDS reads was null (theory
// falsified); r12's 16-row structure restored permanently. r15 micro-add:
// setprio(1) around MFMA clusters (guide T5: +4-7% on attn with wave role
// diversity; our CUs host 2 independent blocks = staging vs MFMA waves coexist).
__global__ __launch_bounds__(256, 2) void attn_kernel(const bf16* __restrict__ qkv,
                                                      const bf16* __restrict__ vt,
                                                      bf16* __restrict__ ctx) {
    __shared__ __align__(16) bf16 Ks[2][64 * 128];    // [key][16B-chunk c ^ (key&7)]
    __shared__ __align__(16) bf16 Vts[2][128 * 64];   // [dh][16B-chunk c ^ (dh&7)]
    __shared__ __align__(16) bf16 Ps[4][16][68];      // per-wave P round-trip

    int flat = blockIdx.y * 16 + blockIdx.x;
    int sid = (flat & 7) * 64 + (flat >> 3);
    int y = sid >> 4;
    int p = sid & 15;
    int b = y >> 4, h = y & 15;
    int t = threadIdx.x, w = t >> 6, l = t & 63;
    int quad = l >> 4, lr = l & 15;

    const bf16* qbase = qkv + (size_t)b * S_ * QKVN + h * DH_;
    const bf16* kbase = qbase + D_;
    const bf16* vbase = vt + (size_t)y * DH_ * S_;

    const int qtA = p, qtB = 31 - p;
    const int nA = p + 1;  // iters for tile A; total 33

    auto stage = [&](int kt, int bi) {
#pragma unroll
        for (int ii = 0; ii < 4; ++ii) {
            int i = 4 * w + ii;
            int row = 4 * i + (l >> 4);
            int cl = (l & 15) ^ (row & 7);
            async_load16(kbase + (size_t)(kt * 64 + row) * QKVN + cl * 8, Ks[bi] + i * 512);
        }
#pragma unroll
        for (int ii = 0; ii < 4; ++ii) {
            int i = 4 * w + ii;
            int dh = 8 * i + (l >> 3);
            int cl = (l & 7) ^ (dh & 7);
            async_load16(vbase + (size_t)dh * S_ + kt * 64 + cl * 8, Vts[bi] + i * 512);
        }
    };

    const float sc2 = 0.12751745f;  // (1/sqrt(128)) * log2(e), folded into Q

    int qt = qtA, q0 = qt * 64;
    bf16x8 qf[4];
    auto loadQ = [&]() {
#pragma unroll
        for (int kk = 0; kk < 4; ++kk) {
            bf16x8 raw = *(const bf16x8*)(qbase + (size_t)(q0 + w * 16 + lr) * QKVN + kk * 32 + quad * 8);
#pragma unroll
            for (int e = 0; e < 8; ++e) qf[kk][e] = (bf16)((float)raw[e] * sc2);
        }
    };
    loadQ();

    float L_r[4];
    f32x4 o[8];
#pragma unroll
    for (int r = 0; r < 4; ++r) L_r[r] = 0.f;
#pragma unroll
    for (int nt = 0; nt < 8; ++nt) o[nt] = (f32x4){0.f, 0.f, 0.f, 0.f};

    auto epilogue = [&](int q0e) {
#pragma unroll
        for (int d = 1; d < 16; d <<= 1)
#pragma unroll
            for (int r = 0; r < 4; ++r) L_r[r] += __shfl_xor(L_r[r], d, 64);
#pragma unroll
        for (int r = 0; r < 4; ++r) {
            float inv = __builtin_amdgcn_rcpf(L_r[r]);
            int q = q0e + w * 16 + quad * 4 + r;
#pragma unroll
            for (int nt = 0; nt < 8; ++nt)
                ctx[(size_t)(b * S_ + q) * D_ + h * DH_ + nt * 16 + lr] = (bf16)(o[nt][r] * inv);
        }
    };

    stage(0, 0);  // prologue

    for (int it = 0; it < 33; ++it) {
        int buf = it & 1;
        asm volatile("s_waitcnt vmcnt(0)" ::: "memory");
        __syncthreads();
        if (it + 1 < 33) {
            int nit = it + 1;
            int nkt = (nit < nA) ? nit : (nit - nA);
            stage(nkt, buf ^ 1);  // in flight across this iter's compute
        }
        int kt = (it < nA) ? it : (it - nA);

        // S = Q K^T: 16 q-rows x 64 keys per wave
        f32x4 s[4];
#pragma unroll
        for (int jt = 0; jt < 4; ++jt) s[jt] = (f32x4){0.f, 0.f, 0.f, 0.f};
        __builtin_amdgcn_s_setprio(1);
#pragma unroll
        for (int kk = 0; kk < 4; ++kk)
#pragma unroll
            for (int jt = 0; jt < 4; ++jt) {
                bf16x8 kf = *(const bf16x8*)(Ks[buf] + (jt * 16 + lr) * 128 + ((4 * kk + quad) ^ (lr & 7)) * 8);
                s[jt] = __builtin_amdgcn_mfma_f32_16x16x32_bf16(qf[kk], kf, s[jt], 0, 0, 0);
            }
        __builtin_amdgcn_s_setprio(0);

        // exp2 (m=0) + mask (diag k-tile only) + per-lane L accumulation + P store
        bool diag = (kt == qt);
#pragma unroll
        for (int jt = 0; jt < 4; ++jt) {
            int keyi = jt * 16 + lr;
#pragma unroll
            for (int r = 0; r < 4; ++r) {
                float s2 = s[jt][r];
                if (diag && keyi > w * 16 + quad * 4 + r) s2 = -3.0e38f;
                float pv = __builtin_amdgcn_exp2f(s2);
                s[jt][r] = pv;
                L_r[r] += pv;
            }
        }
#pragma unroll
        for (int jt = 0; jt < 4; ++jt)
#pragma unroll
            for (int r = 0; r < 4; ++r)
                Ps[w][quad * 4 + r][jt * 16 + lr] = (bf16)s[jt][r];
        asm volatile("s_waitcnt lgkmcnt(0)" ::: "memory");  // per-wave Ps region

        // O += P @ V
        __builtin_amdgcn_s_setprio(1);
#pragma unroll
        for (int ks = 0; ks < 2; ++ks) {
            const bf16* pp = &Ps[w][lr][ks * 32 + quad * 8];
            bf16x4 lo = *(const bf16x4*)pp;
            bf16x4 hi = *(const bf16x4*)(pp + 4);
            bf16x8 pf = __builtin_shufflevector(lo, hi, 0, 1, 2, 3, 4, 5, 6, 7);
#pragma unroll
            for (int nt = 0; nt < 8; ++nt) {
                bf16x8 vf = *(const bf16x8*)(Vts[buf] + (nt * 16 + lr) * 64 + ((4 * ks + quad) ^ (lr & 7)) * 8);
                o[nt] = __builtin_amdgcn_mfma_f32_16x16x32_bf16(pf, vf, o[nt], 0, 0, 0);
            }
        }
        __builtin_amdgcn_s_setprio(0);

        // tile switch A -> B after A's diagonal iteration
        if (it == nA - 1) {
            epilogue(q0);
            qt = qtB;
            q0 = qt * 64;
            loadQ();
#pragma unroll
            for (int r = 0; r < 4; ++r) L_r[r] = 0.f;
#pragma unroll
            for (int nt = 0; nt < 8; ++nt) o[nt] = (f32x4){0.f, 0.f, 0.f, 0.f};
        }
    }

    epilogue(q0);  // tile B
}

extern "C" void kernel_launch(void* const* d_in, const int* in_sizes, int n_in,
                              void* d_out, int out_size, void* d_ws, size_t ws_size,
                              hipStream_t stream) {
    const float* x  = (const float*)d_in[0];
    const float* Wq = (const float*)d_in[1];
    const float* Wk = (const float*)d_in[2];
    const float* Wv = (const float*)d_in[3];
    const float* Wo = (const float*)d_in[4];
    float* out = (float*)d_out;

    char* ws = (char*)d_ws;
    bf16* WqkvT = (bf16*)(ws);                       // 3*2048*2048*2 = 25165824
    bf16* WoT   = (bf16*)(ws + 25165824);            // 2048*2048*2   =  8388608
    bf16* qkv   = (bf16*)(ws + 33554432);            // 4096*6144*2   = 50331648
    bf16* vt    = (bf16*)(ws + 83886080);            // 32*128*2048*2 = 16777216
    bf16* ctx   = (bf16*)(ws + 100663296);           // 4096*2048*2   = 16777216
    bf16* xb    = (bf16*)(ws + 117440512);           // 4096*2048*2   = 16777216
    // total ws use: 134217728 bytes (128 MiB)

    prep_kernel<<<8192, 256, 0, stream>>>(x, Wq, Wk, Wv, Wo, xb, WqkvT, WoT);
    gemm_256x128<48, bf16><<<dim3(768), 512, 0, stream>>>(xb, WqkvT, qkv, vt);
    attn_kernel<<<dim3(16, 32), 256, 0, stream>>>(qkv, vt, ctx);
    gemm_256x128<16, float><<<dim3(256), 512, 0, stream>>>(ctx, WoT, out, nullptr);
}